// Round 1
// baseline (464.117 us; speedup 1.0000x reference)
//
#include <hip/hip_runtime.h>
#include <math.h>

// Problem constants (fixed by setup_inputs): B=8, C=16, S=64, HID=32
#define SD   64
#define NC   16
#define NHID 32
#define NB   8

// x layout (B, C, D, H, W); voxel offset within a (b,c) volume:
//   (d<<12) + (h<<6) + w      (64^3 = 1<<18 elements per channel-volume)

// Kernel 1: Sobel(separable, wrap) -> perc -> MLP -> y = x + dy*upd
// One wave (64 lanes) owns one (b,d,h) row of 64 w-positions; w-dimension
// handled by lane index, wrap via __shfl (S == wavefront size == 64).
__global__ __launch_bounds__(256) void nca_step(
    const float* __restrict__ x, const float* __restrict__ rm,
    const float* __restrict__ W1, const float* __restrict__ b1,
    const float* __restrict__ W2, float* __restrict__ y,
    float* __restrict__ alpha)
{
    const int lane = threadIdx.x & 63;                 // w
    const int r    = blockIdx.x * 4 + (threadIdx.x >> 6);
    const int h    = r & 63;
    const int d    = (r >> 6) & 63;
    const int b    = r >> 12;

    const int dm = (d + 63) & 63, dp = (d + 1) & 63;   // wrap in d
    const int hm = (h + 63) & 63, hp = (h + 1) & 63;   // wrap in h
    const int lm = (lane + 63) & 63, lp = (lane + 1) & 63;  // wrap in w (lane)

    float perc[64];   // [gx(16) | gy(16) | gz(16) | x(16)]

    #pragma unroll
    for (int c = 0; c < NC; ++c) {
        const float* base = x + (((size_t)(b * NC + c)) << 18);
        // 9 coalesced row loads (d+/-1, h+/-1)
        float v_mm = base[(dm << 12) + (hm << 6) + lane];
        float v_m0 = base[(dm << 12) + (h  << 6) + lane];
        float v_mp = base[(dm << 12) + (hp << 6) + lane];
        float v_0m = base[(d  << 12) + (hm << 6) + lane];
        float v_00 = base[(d  << 12) + (h  << 6) + lane];
        float v_0p = base[(d  << 12) + (hp << 6) + lane];
        float v_pm = base[(dp << 12) + (hm << 6) + lane];
        float v_p0 = base[(dp << 12) + (h  << 6) + lane];
        float v_pp = base[(dp << 12) + (hp << 6) + lane];
        // h-direction partials per d-slice
        float am = v_mm + 2.f * v_m0 + v_mp;   // H over h, d-1
        float a0 = v_0m + 2.f * v_00 + v_0p;   // H over h, d
        float ap = v_pm + 2.f * v_p0 + v_pp;   // H over h, d+1
        float gm = v_mp - v_mm;                // G over h, d-1
        float g0 = v_0p - v_0m;
        float gp = v_pp - v_pm;
        // d-direction combine
        float P_hh = am + 2.f * a0 + ap;       // H_d H_h
        float P_hg = gm + 2.f * g0 + gp;       // H_d G_h
        float P_gh = ap - am;                  // G_d H_h
        // w-direction finish via lane shuffles (wrap = &63)
        float gx = __shfl(P_hh, lp, 64) - __shfl(P_hh, lm, 64);          // H H G
        float gy = __shfl(P_hg, lm, 64) + 2.f * P_hg + __shfl(P_hg, lp, 64); // H G H
        float gz = __shfl(P_gh, lm, 64) + 2.f * P_gh + __shfl(P_gh, lp, 64); // G H H
        perc[c]          = gx;
        perc[NC + c]     = gy;
        perc[2 * NC + c] = gz;
        perc[3 * NC + c] = v_00;
    }

    // MLP: h_o = relu(W1[o,:] . perc + b1[o]);  dy[ch] = sum_o W2[ch,o] * h_o
    float dyv[NC];
    #pragma unroll
    for (int ch = 0; ch < NC; ++ch) dyv[ch] = 0.f;

    #pragma unroll 4
    for (int o = 0; o < NHID; ++o) {
        const float* wrow = W1 + (o << 6);     // wave-uniform -> s_load
        float acc = b1[o];
        #pragma unroll
        for (int cc = 0; cc < 64; ++cc)
            acc = fmaf(wrow[cc], perc[cc], acc);
        acc = fmaxf(acc, 0.f);
        #pragma unroll
        for (int ch = 0; ch < NC; ++ch)
            dyv[ch] = fmaf(W2[(ch << 5) + o], acc, dyv[ch]);
    }

    // y = x + dy * floor(rm + 0.25); write y, and alpha = y[:,3]
    const size_t voff = ((size_t)(d) << 12) + ((size_t)h << 6) + lane;
    #pragma unroll
    for (int ch = 0; ch < NC; ++ch) {
        const size_t idx = (((size_t)(b * NC + ch)) << 18) + voff;
        float upd = floorf(rm[idx] + 0.25f);
        float yv  = perc[3 * NC + ch] + dyv[ch] * upd;
        y[idx] = yv;
        if (ch == 3) alpha[(((size_t)b) << 18) + voff] = yv;
    }
}

// Kernel 2: 3x3x3 max-pool of alpha with -inf padding (NO wrap), then
// out *= (pooled > 0.1) over all 16 channels. In-place RMW of d_out is
// safe: each thread touches only its own elements; alpha is a separate
// read-only copy in d_ws.
__global__ __launch_bounds__(256) void alive_mask(
    const float* __restrict__ alpha, float* __restrict__ y)
{
    const int lane = threadIdx.x & 63;
    const int r    = blockIdx.x * 4 + (threadIdx.x >> 6);
    const int h    = r & 63;
    const int d    = (r >> 6) & 63;
    const int b    = r >> 12;

    const float* ab = alpha + (((size_t)b) << 18);
    float m = -INFINITY;
    #pragma unroll
    for (int dz = -1; dz <= 1; ++dz) {
        int dd = d + dz;
        if (dd < 0 || dd > 63) continue;   // -inf border (padding, not wrap)
        #pragma unroll
        for (int hy = -1; hy <= 1; ++hy) {
            int hh = h + hy;
            if (hh < 0 || hh > 63) continue;
            m = fmaxf(m, ab[(dd << 12) + (hh << 6) + lane]);
        }
    }
    // w-direction: shuffle with -inf at the row ends
    const int lmm = (lane + 63) & 63, lpp = (lane + 1) & 63;
    float left  = __shfl(m, lmm, 64);
    float right = __shfl(m, lpp, 64);
    if (lane == 0)  left  = -INFINITY;
    if (lane == 63) right = -INFINITY;
    float pooled = fmaxf(m, fmaxf(left, right));
    float alive  = (pooled > 0.1f) ? 1.0f : 0.0f;

    const size_t voff = ((size_t)(d) << 12) + ((size_t)h << 6) + lane;
    #pragma unroll
    for (int ch = 0; ch < NC; ++ch) {
        const size_t idx = (((size_t)(b * NC + ch)) << 18) + voff;
        y[idx] *= alive;
    }
}

extern "C" void kernel_launch(void* const* d_in, const int* in_sizes, int n_in,
                              void* d_out, int out_size, void* d_ws, size_t ws_size,
                              hipStream_t stream) {
    const float* x  = (const float*)d_in[0];
    const float* rm = (const float*)d_in[1];
    const float* W1 = (const float*)d_in[2];
    const float* b1 = (const float*)d_in[3];
    const float* W2 = (const float*)d_in[4];
    float* y     = (float*)d_out;
    float* alpha = (float*)d_ws;   // needs 8*64^3*4 = 8 MB of scratch

    const int rows   = NB * SD * SD;        // 32768 (b,d,h) rows
    const int blocks = rows / 4;            // 4 rows (waves) per 256-thread block

    nca_step<<<blocks, 256, 0, stream>>>(x, rm, W1, b1, W2, y, alpha);
    alive_mask<<<blocks, 256, 0, stream>>>(alpha, y);
}

// Round 2
// 441.931 us; speedup vs baseline: 1.0502x; 1.0502x over previous
//
#include <hip/hip_runtime.h>
#include <math.h>

// Problem constants (fixed by setup_inputs): B=8, C=16, S=64, HID=32
#define SD   64
#define NC   16
#define NHID 32
#define NB   8

// Kernel 1: Sobel(separable, wrap) -> MLP -> y = x + dy*upd
// One wave (64 lanes) owns one (b,d,h) row; w-dim = lane, wrap via __shfl.
// MLP restructured: NO perc[64] array (R1 spilled it to AGPRs at VGPR=56,
// ~2048 extra v_accvgpr_read ops). Each channel's gx/gy/gz/x contributions
// are accumulated straight into hacc[32]; live set ~70 regs.
// __launch_bounds__(256,4): min 4 waves/EU -> VGPR cap 128, no spill.
__global__ __launch_bounds__(256, 4) void nca_step(
    const float* __restrict__ x, const float* __restrict__ rm,
    const float* __restrict__ W1, const float* __restrict__ b1,
    const float* __restrict__ W2, float* __restrict__ y,
    float* __restrict__ alpha)
{
    const int lane = threadIdx.x & 63;                 // w
    const int r    = blockIdx.x * 4 + (threadIdx.x >> 6);
    const int h    = r & 63;
    const int d    = (r >> 6) & 63;
    const int b    = r >> 12;

    const int dm = (d + 63) & 63, dp = (d + 1) & 63;   // wrap in d
    const int hm = (h + 63) & 63, hp = (h + 1) & 63;   // wrap in h
    const int lm = (lane + 63) & 63, lp = (lane + 1) & 63;  // wrap in w

    // 9 row offsets, shared across all channels
    const int o_mm = (dm << 12) + (hm << 6) + lane;
    const int o_m0 = (dm << 12) + (h  << 6) + lane;
    const int o_mp = (dm << 12) + (hp << 6) + lane;
    const int o_0m = (d  << 12) + (hm << 6) + lane;
    const int o_00 = (d  << 12) + (h  << 6) + lane;
    const int o_0p = (d  << 12) + (hp << 6) + lane;
    const int o_pm = (dp << 12) + (hm << 6) + lane;
    const int o_p0 = (dp << 12) + (h  << 6) + lane;
    const int o_pp = (dp << 12) + (hp << 6) + lane;

    float hacc[NHID];
    #pragma unroll
    for (int o = 0; o < NHID; ++o) hacc[o] = b1[o];

    float xv[NC];   // keep center x for the residual add

    #pragma unroll
    for (int c = 0; c < NC; ++c) {
        const float* base = x + (((size_t)(b * NC + c)) << 18);
        float v_mm = base[o_mm], v_m0 = base[o_m0], v_mp = base[o_mp];
        float v_0m = base[o_0m], v_00 = base[o_00], v_0p = base[o_0p];
        float v_pm = base[o_pm], v_p0 = base[o_p0], v_pp = base[o_pp];
        // h-direction partials per d-slice
        float am = v_mm + 2.f * v_m0 + v_mp;
        float a0 = v_0m + 2.f * v_00 + v_0p;
        float ap = v_pm + 2.f * v_p0 + v_pp;
        float gm = v_mp - v_mm;
        float g0 = v_0p - v_0m;
        float gp = v_pp - v_pm;
        // d-direction combine
        float P_hh = am + 2.f * a0 + ap;       // H_d H_h
        float P_hg = gm + 2.f * g0 + gp;       // H_d G_h
        float P_gh = ap - am;                  // G_d H_h
        // w-direction finish via lane shuffles (wrap = &63)
        float gx = __shfl(P_hh, lp, 64) - __shfl(P_hh, lm, 64);              // H H G
        float gy = __shfl(P_hg, lm, 64) + 2.f * P_hg + __shfl(P_hg, lp, 64); // H G H
        float gz = __shfl(P_gh, lm, 64) + 2.f * P_gh + __shfl(P_gh, lp, 64); // G H H
        xv[c] = v_00;
        // accumulate this channel's 4 features into all 32 hidden units;
        // W1 indices are wave-uniform -> s_load scalar operands
        #pragma unroll
        for (int o = 0; o < NHID; ++o) {
            float t = fmaf(W1[(o << 6) + c],          gx,   hacc[o]);
            t       = fmaf(W1[(o << 6) + NC + c],     gy,   t);
            t       = fmaf(W1[(o << 6) + 2 * NC + c], gz,   t);
            hacc[o] = fmaf(W1[(o << 6) + 3 * NC + c], v_00, t);
        }
    }

    // relu + second layer
    float dyv[NC];
    #pragma unroll
    for (int ch = 0; ch < NC; ++ch) dyv[ch] = 0.f;
    #pragma unroll
    for (int o = 0; o < NHID; ++o) {
        float a = fmaxf(hacc[o], 0.f);
        #pragma unroll
        for (int ch = 0; ch < NC; ++ch)
            dyv[ch] = fmaf(W2[(ch << 5) + o], a, dyv[ch]);
    }

    // y = x + dy * floor(rm + 0.25); write y, and alpha = y[:,3]
    const size_t voff = ((size_t)d << 12) + ((size_t)h << 6) + lane;
    #pragma unroll
    for (int ch = 0; ch < NC; ++ch) {
        const size_t idx = (((size_t)(b * NC + ch)) << 18) + voff;
        float upd = floorf(rm[idx] + 0.25f);
        float yv  = fmaf(dyv[ch], upd, xv[ch]);
        y[idx] = yv;
        if (ch == 3) alpha[(((size_t)b) << 18) + voff] = yv;
    }
}

// Kernel 2: 3x3x3 max-pool of alpha (-inf borders, NO wrap), then
// y *= (pooled > 0.1) for all 16 channels. float4-vectorized along w:
// each thread owns 4 consecutive w, so the 16-channel RMW is 16B/op.
__global__ __launch_bounds__(256, 4) void alive_mask(
    const float* __restrict__ alpha, float* __restrict__ y)
{
    const int tid  = blockIdx.x * 256 + threadIdx.x;
    const int lane = threadIdx.x & 63;
    const int wq   = tid & 15;          // which float4 in the row
    const int w4   = wq << 2;
    const int h    = (tid >> 4) & 63;
    const int d    = (tid >> 10) & 63;
    const int b    = tid >> 16;

    const float* ab = alpha + (((size_t)b) << 18);

    float m0 = -INFINITY, m1 = -INFINITY, m2 = -INFINITY, m3 = -INFINITY;
    #pragma unroll
    for (int dz = -1; dz <= 1; ++dz) {
        int dd = d + dz;
        if (dd < 0 || dd > 63) continue;   // -inf border (padding, not wrap)
        #pragma unroll
        for (int hy = -1; hy <= 1; ++hy) {
            int hh = h + hy;
            if (hh < 0 || hh > 63) continue;
            const float4 v = *reinterpret_cast<const float4*>(
                ab + (dd << 12) + (hh << 6) + w4);
            m0 = fmaxf(m0, v.x); m1 = fmaxf(m1, v.y);
            m2 = fmaxf(m2, v.z); m3 = fmaxf(m3, v.w);
        }
    }
    // w-direction: neighbors via lane shuffle; wave lanes 0..15 = one row,
    // row-crossing shuffles are exactly the wq==0 / wq==15 cases -> -inf.
    float left  = __shfl(m3, (lane + 63) & 63, 64);
    float right = __shfl(m0, (lane + 1) & 63, 64);
    if (wq == 0)  left  = -INFINITY;
    if (wq == 15) right = -INFINITY;

    float p0 = fmaxf(left, fmaxf(m0, m1));
    float p1 = fmaxf(m0,   fmaxf(m1, m2));
    float p2 = fmaxf(m1,   fmaxf(m2, m3));
    float p3 = fmaxf(m2,   fmaxf(m3, right));
    float a0 = (p0 > 0.1f) ? 1.f : 0.f;
    float a1 = (p1 > 0.1f) ? 1.f : 0.f;
    float a2 = (p2 > 0.1f) ? 1.f : 0.f;
    float a3 = (p3 > 0.1f) ? 1.f : 0.f;

    const size_t voff = ((size_t)d << 12) + ((size_t)h << 6) + w4;
    #pragma unroll
    for (int ch = 0; ch < NC; ++ch) {
        float4* p = reinterpret_cast<float4*>(
            y + (((size_t)(b * NC + ch)) << 18) + voff);
        float4 v = *p;
        v.x *= a0; v.y *= a1; v.z *= a2; v.w *= a3;
        *p = v;
    }
}

extern "C" void kernel_launch(void* const* d_in, const int* in_sizes, int n_in,
                              void* d_out, int out_size, void* d_ws, size_t ws_size,
                              hipStream_t stream) {
    const float* x  = (const float*)d_in[0];
    const float* rm = (const float*)d_in[1];
    const float* W1 = (const float*)d_in[2];
    const float* b1 = (const float*)d_in[3];
    const float* W2 = (const float*)d_in[4];
    float* y     = (float*)d_out;
    float* alpha = (float*)d_ws;   // 8 * 64^3 * 4 = 8 MB scratch

    const int rows    = NB * SD * SD;       // 32768 (b,d,h) rows
    const int blocks1 = rows / 4;           // 4 waves (rows) per block
    const int blocks2 = (NB * SD * SD * 16) / 256;  // 4 voxels per thread

    nca_step<<<blocks1, 256, 0, stream>>>(x, rm, W1, b1, W2, y, alpha);
    alive_mask<<<blocks2, 256, 0, stream>>>(alpha, y);
}